// Round 1
// baseline (778.720 us; speedup 1.0000x reference)
//
#include <hip/hip_runtime.h>

#define TT 32768          // tokens
#define HH 2048           // hidden
#define NE 64             // experts
#define TOPK 8
#define BK 64             // K-chunk
#define TM 64             // tokens per workgroup

#define W_OFF 0
#define I_OFF (TT * TOPK)                 // 262144
#define P_OFF (2 * TT * TOPK)             // 524288
#define B_OFF (P_OFF + (size_t)TT * NE)   // 2621440

// ---------------------------------------------------------------------------
// Main fused kernel: gate GEMM + jitter/bias + softmax + top-8 + counts
// Grid: 512 blocks x 256 threads. Each block: 64 tokens x 64 experts.
// ---------------------------------------------------------------------------
__global__ __launch_bounds__(256, 2) void router_fused(
    const float* __restrict__ x, const float* __restrict__ gw,
    const float* __restrict__ eb, const float* __restrict__ noise,
    float* __restrict__ out, int* __restrict__ counts)
{
    // +4 float pad: inter-row stride 68 ≡ 4 (mod 32) banks -> <=2-way aliasing (free)
    __shared__ __align__(16) float xs[TM][BK + 4];
    __shared__ __align__(16) float ws[NE][BK + 4];
    __shared__ int lc[NE];

    const int tid = threadIdx.x;
    const int tx = tid & 15;          // expert group: experts {tx + 16j}
    const int ty = tid >> 4;          // token group:  tokens  {4*ty + i}
    const int tok0 = blockIdx.x * TM;

    float acc[4][4];
#pragma unroll
    for (int i = 0; i < 4; ++i)
#pragma unroll
        for (int j = 0; j < 4; ++j) acc[i][j] = 0.f;

    const int r = tid >> 4;           // staging row 0..15
    const int c = (tid & 15) << 2;    // staging col (floats)

    for (int k0 = 0; k0 < HH; k0 += BK) {
#pragma unroll
        for (int rr = 0; rr < TM; rr += 16) {
            *(float4*)&xs[r + rr][c] =
                *(const float4*)&x[(size_t)(tok0 + r + rr) * HH + k0 + c];
            *(float4*)&ws[r + rr][c] =
                *(const float4*)&gw[(size_t)(r + rr) * HH + k0 + c];
        }
        __syncthreads();
#pragma unroll
        for (int kk = 0; kk < BK; kk += 4) {
            float4 a[4], b[4];
#pragma unroll
            for (int i = 0; i < 4; ++i) a[i] = *(const float4*)&xs[4 * ty + i][kk];
#pragma unroll
            for (int j = 0; j < 4; ++j) b[j] = *(const float4*)&ws[tx + 16 * j][kk];
#pragma unroll
            for (int i = 0; i < 4; ++i)
#pragma unroll
                for (int j = 0; j < 4; ++j)
                    acc[i][j] += a[i].x * b[j].x + a[i].y * b[j].y +
                                 a[i].z * b[j].z + a[i].w * b[j].w;
        }
        __syncthreads();
    }

    // Stash logits in LDS (reuse xs storage), stride 65 -> 2-way bank aliasing
    float* lg = &xs[0][0];
#pragma unroll
    for (int i = 0; i < 4; ++i)
#pragma unroll
        for (int j = 0; j < 4; ++j)
            lg[(4 * ty + i) * 65 + (tx + 16 * j)] = acc[i][j];
    if (tid < NE) lc[tid] = 0;
    __syncthreads();

    // Wave 0: one lane per token does softmax + top-8
    if (tid < TM) {
        const int t = tok0 + tid;
        float* row = &lg[tid * 65];

        float vmax = -1e30f;
#pragma unroll 8
        for (int e = 0; e < NE; ++e) {
            float v = row[e] + noise[(size_t)t * NE + e] * 0.01f + eb[e];
            row[e] = v;
            vmax = fmaxf(vmax, v);
        }
        float s = 0.f;
#pragma unroll 8
        for (int e = 0; e < NE; ++e) {
            float p = expf(row[e] - vmax);
            row[e] = p;
            s += p;
        }
        const float inv = 1.f / s;
#pragma unroll 8
        for (int e = 0; e < NE; ++e) {
            float p = row[e] * inv;
            row[e] = p;
            out[P_OFF + (size_t)t * NE + e] = p;
        }

        float tw[TOPK]; int ti[TOPK];
        float wsum = 0.f;
        for (int k = 0; k < TOPK; ++k) {
            float best = -1.f; int bi = 0;
            for (int e = 0; e < NE; ++e) {
                float p = row[e];
                if (p > best) { best = p; bi = e; }   // strict > => lowest index on ties
            }
            row[bi] = -2.f;
            tw[k] = best; ti[k] = bi; wsum += best;
        }
        const float winv = 1.f / wsum;
#pragma unroll
        for (int k = 0; k < TOPK; ++k) {
            out[W_OFF + t * TOPK + k] = tw[k] * winv;
            out[I_OFF + t * TOPK + k] = (float)ti[k];
            atomicAdd(&lc[ti[k]], 1);
        }
    }
    __syncthreads();
    if (tid < NE) {
        int v = lc[tid];
        if (v) atomicAdd(&counts[tid], v);
    }
}

__global__ void zero_counts_k(int* c)
{
    if (threadIdx.x < NE) c[threadIdx.x] = 0;
}

// sign(load - 1/64) computed exactly: counts/2^18 is exact in fp32
__global__ void bias_k(const int* __restrict__ c, const float* __restrict__ eb,
                       float* __restrict__ out)
{
    int e = threadIdx.x;
    if (e < NE) {
        float load = (float)c[e] * (1.0f / 262144.0f);
        float err = load - 0.015625f;
        float sg = (err > 0.f) ? 1.f : ((err < 0.f) ? -1.f : 0.f);
        out[B_OFF + e] = eb[e] - 0.001f * sg;
    }
}

extern "C" void kernel_launch(void* const* d_in, const int* in_sizes, int n_in,
                              void* d_out, int out_size, void* d_ws, size_t ws_size,
                              hipStream_t stream)
{
    const float* x     = (const float*)d_in[0];
    const float* gw    = (const float*)d_in[1];
    const float* eb    = (const float*)d_in[2];
    const float* noise = (const float*)d_in[3];
    float* out = (float*)d_out;
    int* counts = (int*)d_ws;

    hipLaunchKernelGGL(zero_counts_k, dim3(1), dim3(64), 0, stream, counts);
    hipLaunchKernelGGL(router_fused, dim3(TT / TM), dim3(256), 0, stream,
                       x, gw, eb, noise, out, counts);
    hipLaunchKernelGGL(bias_k, dim3(1), dim3(64), 0, stream, counts, eb, out);
}

// Round 3
// 727.384 us; speedup vs baseline: 1.0706x; 1.0706x over previous
//
#include <hip/hip_runtime.h>

#define TT 32768          // tokens
#define HH 2048           // hidden
#define NE 64             // experts
#define TOPK 8
#define BK 128            // K-chunk (floats)
#define NC (HH / BK)      // 16 chunks

#define W_OFF 0
#define I_OFF (TT * TOPK)                 // 262144
#define P_OFF (2 * TT * TOPK)             // 524288
#define B_OFF (P_OFF + (size_t)TT * NE)   // 2621440

// ---------------------------------------------------------------------------
// Block: 256 threads = 4 waves. Block owns 64 tokens x 64 experts.
// GEMM phase: lane = token; wave w owns experts [16w,16w+16).
//   x: one swizzled ds_read_b128 per lane per 4-k step (conflict-free).
//   gw: wave-uniform address -> scalar/broadcast loads, L2-resident (512 KB).
//   Inner expression is EXACTLY R1's (passed):  acc += ax*bx+ay*by+az*bz+aw*bw
//   -- ranking vs np ref is determined by this arithmetic; do not change it.
// Epilogue: lane = expert; wave w owns tokens [16w,16w+16). Butterfly
//   reductions are selection-equivalent to R1's serial scans.
// ---------------------------------------------------------------------------
__global__ __launch_bounds__(256, 2) void router_fused(
    const float* __restrict__ x, const float* __restrict__ gw,
    const float* __restrict__ eb, const float* __restrict__ noise,
    float* __restrict__ out, int* __restrict__ counts)
{
    // xs: 64 rows x 32 float4 groups, XOR-swizzled. Reused as logits
    // (64 x stride-65) after the GEMM loop (barrier-separated).
    __shared__ __align__(16) float xs[64 * BK];
    __shared__ int lc[NE];
    float* lgs = xs;                              // alias: 64*65 = 4160 <= 8192

    const int tid = threadIdx.x;
    const int lane = tid & 63;
    const int wv = __builtin_amdgcn_readfirstlane(tid >> 6);
    const int e0 = wv * 16;
    const int tok0 = blockIdx.x * 64;

    float4* xs4 = (float4*)xs;

    float acc[16];
#pragma unroll
    for (int i = 0; i < 16; ++i) acc[i] = 0.f;

    if (tid < NE) lc[tid] = 0;

    // register-prefetch staging: store group f of row r at slot (f ^ (r&31))
    float4 pre[8];
#pragma unroll
    for (int it = 0; it < 8; ++it) {
        int idx = it * 256 + tid;
        int r = idx >> 5, f = idx & 31;
        pre[it] = *(const float4*)&x[(size_t)(tok0 + r) * HH + f * 4];
    }

    for (int c = 0; c < NC; ++c) {
        __syncthreads();                       // prev compute done, xs free
#pragma unroll
        for (int it = 0; it < 8; ++it) {
            int idx = it * 256 + tid;
            int r = idx >> 5, f = idx & 31;
            xs4[r * 32 + (f ^ (r & 31))] = pre[it];
        }
        __syncthreads();                       // tile ready
        if (c + 1 < NC) {
            const int k0n = (c + 1) * BK;
#pragma unroll
            for (int it = 0; it < 8; ++it) {
                int idx = it * 256 + tid;
                int r = idx >> 5, f = idx & 31;
                pre[it] = *(const float4*)&x[(size_t)(tok0 + r) * HH + k0n + f * 4];
            }
        }
        const int k0 = c * BK;
        for (int kk = 0; kk < BK; kk += 4) {
            const float4 xv = xs4[lane * 32 + ((kk >> 2) ^ (lane & 31))];
#pragma unroll
            for (int i = 0; i < 16; ++i) {
                const float4 g = *(const float4*)&gw[(size_t)(e0 + i) * HH + k0 + kk];
                acc[i] += xv.x * g.x + xv.y * g.y + xv.z * g.z + xv.w * g.w;
            }
        }
    }

    // redistribute logits: lane=token -> lane=expert (xs reused as lgs)
    __syncthreads();
#pragma unroll
    for (int i = 0; i < 16; ++i) lgs[lane * 65 + e0 + i] = acc[i];
    __syncthreads();

    // epilogue: wave wv handles tokens [16wv,16wv+16), lane = expert
    const int e = lane;
    const float ebv = eb[e];
    int cnt = 0;
    for (int tt = 0; tt < 16; ++tt) {
        const int t = wv * 16 + tt;
        const int gt = tok0 + t;
        float v = lgs[t * 65 + e] + noise[(size_t)gt * NE + e] * 0.01f + ebv;

        float m = v;
#pragma unroll
        for (int s = 1; s < 64; s <<= 1) m = fmaxf(m, __shfl_xor(m, s, 64));
        float pu = expf(v - m);                 // unnormalized, as R1
        float ssum = pu;
#pragma unroll
        for (int s = 1; s < 64; s <<= 1) ssum += __shfl_xor(ssum, s, 64);
        const float inv = 1.f / ssum;           // as R1: multiply by reciprocal
        float p = pu * inv;
        out[P_OFF + (size_t)gt * NE + e] = p;   // coalesced 256B per token

        float pw = p;
        float myw = 0.f; int myi = 0;
        float wsum = 0.f;
#pragma unroll
        for (int r = 0; r < TOPK; ++r) {
            float bv = pw; int bi = e;
#pragma unroll
            for (int s = 1; s < 64; s <<= 1) {
                float ov = __shfl_xor(bv, s, 64);
                int   oi = __shfl_xor(bi, s, 64);
                if (ov > bv || (ov == bv && oi < bi)) { bv = ov; bi = oi; }
            }
            wsum += bv;                          // all lanes agree on winner
            if (lane == r) { myw = bv; myi = bi; }
            if (e == bi) { pw = -1.f; cnt++; }   // knock out + local count
        }
        if (lane < TOPK) {
            const float winv = 1.f / wsum;
            out[W_OFF + (size_t)gt * TOPK + lane] = myw * winv;
            out[I_OFF + (size_t)gt * TOPK + lane] = (float)myi;
        }
    }
    if (cnt) atomicAdd(&lc[e], cnt);
    __syncthreads();
    if (tid < NE) { int vv = lc[tid]; if (vv) atomicAdd(&counts[tid], vv); }
}

__global__ void zero_counts_k(int* c)
{
    if (threadIdx.x < NE) c[threadIdx.x] = 0;
}

// sign(load - 1/64) computed exactly: counts/2^18 is exact in fp32
__global__ void bias_k(const int* __restrict__ c, const float* __restrict__ eb,
                       float* __restrict__ out)
{
    int e = threadIdx.x;
    if (e < NE) {
        float load = (float)c[e] * (1.0f / 262144.0f);
        float err = load - 0.015625f;
        float sg = (err > 0.f) ? 1.f : ((err < 0.f) ? -1.f : 0.f);
        out[B_OFF + e] = eb[e] - 0.001f * sg;
    }
}

extern "C" void kernel_launch(void* const* d_in, const int* in_sizes, int n_in,
                              void* d_out, int out_size, void* d_ws, size_t ws_size,
                              hipStream_t stream)
{
    const float* x     = (const float*)d_in[0];
    const float* gw    = (const float*)d_in[1];
    const float* eb    = (const float*)d_in[2];
    const float* noise = (const float*)d_in[3];
    float* out = (float*)d_out;
    int* counts = (int*)d_ws;

    hipLaunchKernelGGL(zero_counts_k, dim3(1), dim3(64), 0, stream, counts);
    hipLaunchKernelGGL(router_fused, dim3(TT / 64), dim3(256), 0, stream,
                       x, gw, eb, noise, out, counts);
    hipLaunchKernelGGL(bias_k, dim3(1), dim3(64), 0, stream, counts, eb, out);
}

// Round 4
// 469.102 us; speedup vs baseline: 1.6600x; 1.5506x over previous
//
#include <hip/hip_runtime.h>

#define TT 32768          // tokens
#define HH 2048           // hidden
#define NE 64             // experts
#define TOPK 8
#define BKC 64            // K-chunk
#define NCH (HH / BKC)    // 32 chunks

#define W_OFF 0
#define I_OFF (TT * TOPK)                 // 262144
#define P_OFF (2 * TT * TOPK)             // 524288
#define B_OFF (P_OFF + (size_t)TT * NE)   // 2621440

typedef __attribute__((ext_vector_type(8))) short short8;
typedef __attribute__((ext_vector_type(4))) float floatx4;

// swizzled ushort index of the 8-bf16 granule (row t, granule g in 0..7):
// granule slot = g ^ (t & 7) -> frag reads and staging writes conflict-free.
#define SWZ(t, g) (((t) << 6) + ((((g) ^ ((t)&7))) << 3))

// Exact truncation split: f = h0 + h1 + h2 + eps, |eps| <~ 2^-22 |f|.
// Subtractions are exact (Sterbenz). Returns packed bf16 bit patterns.
__device__ __forceinline__ void split3(const float4 v, ushort4& o0, ushort4& o1, ushort4& o2)
{
    const float* vf = (const float*)&v;
    ushort* p0 = (ushort*)&o0; ushort* p1 = (ushort*)&o1; ushort* p2 = (ushort*)&o2;
#pragma unroll
    for (int i = 0; i < 4; ++i) {
        float f = vf[i];
        unsigned u0 = __float_as_uint(f);
        float h0 = __uint_as_float(u0 & 0xffff0000u);
        float r1 = f - h0;
        unsigned u1 = __float_as_uint(r1);
        float h1 = __uint_as_float(u1 & 0xffff0000u);
        float r2 = r1 - h1;
        unsigned u2 = __float_as_uint(r2);
        p0[i] = (ushort)(u0 >> 16);
        p1[i] = (ushort)(u1 >> 16);
        p2[i] = (ushort)(u2 >> 16);
    }
}

// ---------------------------------------------------------------------------
// Block: 256 thr = 4 waves; 64 tokens x 64 experts; K chunked by 64.
// GEMM via mfma_f32_16x16x32_bf16 on 3-way exact bf16 splits of x and gw:
//   logit = [x0*g0] + [x0*g1 + x1*g0 + x0*g2 + x1*g1 + x2*g0]   (accB + accS)
// dropped terms ~2^-24 rel; accB rounding ~= plain fp32 dot (R1-class).
// Wave (wm,wn) owns token-tiles {2wm,2wm+1}, expert-tiles {2wn,2wn+1}.
// Epilogue identical to R3 (verified): wave wv -> tokens [16wv,16wv+16),
// lane = expert, butterfly softmax/top-8, coalesced writes.
// ---------------------------------------------------------------------------
__global__ __launch_bounds__(256, 2) void router_fused(
    const float* __restrict__ x, const float* __restrict__ gw,
    const float* __restrict__ eb, const float* __restrict__ noise,
    float* __restrict__ out, int* __restrict__ counts)
{
    __shared__ ushort xp[3][64 * 64];   // x  bf16 planes, swizzled (8 KB each)
    __shared__ ushort gp[3][64 * 64];   // gw bf16 planes
    __shared__ float lgs[64 * 65];
    __shared__ int lc[NE];

    const int tid = threadIdx.x;
    const int lane = tid & 63;
    const int wv = tid >> 6;
    const int wm = wv & 1, wn = wv >> 1;
    const int lr = lane & 15;           // row-in-tile (token / expert)
    const int lq = lane >> 4;           // quad
    const int tok0 = blockIdx.x * 64;

    floatx4 accB[2][2], accS[2][2];
#pragma unroll
    for (int i = 0; i < 2; ++i)
#pragma unroll
        for (int j = 0; j < 2; ++j) { accB[i][j] = (floatx4)0.f; accS[i][j] = (floatx4)0.f; }

    if (tid < NE) lc[tid] = 0;

    const int sr = tid >> 4;            // staging sub-row 0..15
    const int sf = tid & 15;            // staging float4-group 0..15

    float4 px[4], pg[4];
#pragma unroll
    for (int it = 0; it < 4; ++it) {
        const int rr = it * 16 + sr;
        px[it] = *(const float4*)&x[(size_t)(tok0 + rr) * HH + sf * 4];
        pg[it] = *(const float4*)&gw[(size_t)rr * HH + sf * 4];
    }

    for (int c = 0; c < NCH; ++c) {
        __syncthreads();                // previous chunk's frag reads done
#pragma unroll
        for (int it = 0; it < 4; ++it) {
            const int rr = it * 16 + sr;
            const int xi = SWZ(rr, sf >> 1) + ((sf & 1) << 2);
            ushort4 a0, a1, a2;
            split3(px[it], a0, a1, a2);
            *(ushort4*)&xp[0][xi] = a0;
            *(ushort4*)&xp[1][xi] = a1;
            *(ushort4*)&xp[2][xi] = a2;
            split3(pg[it], a0, a1, a2);
            *(ushort4*)&gp[0][xi] = a0;
            *(ushort4*)&gp[1][xi] = a1;
            *(ushort4*)&gp[2][xi] = a2;
        }
        __syncthreads();                // planes ready
        if (c + 1 < NCH) {
            const int k0 = (c + 1) * BKC;
#pragma unroll
            for (int it = 0; it < 4; ++it) {
                const int rr = it * 16 + sr;
                px[it] = *(const float4*)&x[(size_t)(tok0 + rr) * HH + k0 + sf * 4];
                pg[it] = *(const float4*)&gw[(size_t)rr * HH + k0 + sf * 4];
            }
        }
#pragma unroll
        for (int s = 0; s < 2; ++s) {
            short8 a[2][3], b[2][3];
            const int g = s * 4 + lq;
#pragma unroll
            for (int mt = 0; mt < 2; ++mt) {
                const int t = wm * 32 + mt * 16 + lr;
                const int ai = SWZ(t, g);
#pragma unroll
                for (int p = 0; p < 3; ++p) a[mt][p] = *(const short8*)&xp[p][ai];
            }
#pragma unroll
            for (int nt = 0; nt < 2; ++nt) {
                const int e = wn * 32 + nt * 16 + lr;
                const int bi = SWZ(e, g);
#pragma unroll
                for (int p = 0; p < 3; ++p) b[nt][p] = *(const short8*)&gp[p][bi];
            }
#pragma unroll
            for (int mt = 0; mt < 2; ++mt)
#pragma unroll
                for (int nt = 0; nt < 2; ++nt) {
                    accB[mt][nt] = __builtin_amdgcn_mfma_f32_16x16x32_bf16(
                        a[mt][0], b[nt][0], accB[mt][nt], 0, 0, 0);
                    accS[mt][nt] = __builtin_amdgcn_mfma_f32_16x16x32_bf16(
                        a[mt][0], b[nt][1], accS[mt][nt], 0, 0, 0);
                    accS[mt][nt] = __builtin_amdgcn_mfma_f32_16x16x32_bf16(
                        a[mt][1], b[nt][0], accS[mt][nt], 0, 0, 0);
                    accS[mt][nt] = __builtin_amdgcn_mfma_f32_16x16x32_bf16(
                        a[mt][0], b[nt][2], accS[mt][nt], 0, 0, 0);
                    accS[mt][nt] = __builtin_amdgcn_mfma_f32_16x16x32_bf16(
                        a[mt][1], b[nt][1], accS[mt][nt], 0, 0, 0);
                    accS[mt][nt] = __builtin_amdgcn_mfma_f32_16x16x32_bf16(
                        a[mt][2], b[nt][0], accS[mt][nt], 0, 0, 0);
                }
        }
    }

    // C/D layout (verified m89/m91): col = lane&15 (expert), row = quad*4+reg
    __syncthreads();
#pragma unroll
    for (int mt = 0; mt < 2; ++mt)
#pragma unroll
        for (int nt = 0; nt < 2; ++nt)
#pragma unroll
            for (int rg = 0; rg < 4; ++rg) {
                const int tok = wm * 32 + mt * 16 + lq * 4 + rg;
                const int e = wn * 32 + nt * 16 + lr;
                lgs[tok * 65 + e] = accB[mt][nt][rg] + accS[mt][nt][rg];
            }
    __syncthreads();

    // ---- epilogue (R3 verbatim): wave wv -> tokens [16wv,16wv+16) ---------
    const int e = lane;
    const float ebv = eb[e];
    int cnt = 0;
    for (int tt = 0; tt < 16; ++tt) {
        const int t = wv * 16 + tt;
        const int gt = tok0 + t;
        float v = lgs[t * 65 + e] + noise[(size_t)gt * NE + e] * 0.01f + ebv;

        float m = v;
#pragma unroll
        for (int s = 1; s < 64; s <<= 1) m = fmaxf(m, __shfl_xor(m, s, 64));
        float pu = expf(v - m);
        float ssum = pu;
#pragma unroll
        for (int s = 1; s < 64; s <<= 1) ssum += __shfl_xor(ssum, s, 64);
        const float inv = 1.f / ssum;
        float p = pu * inv;
        out[P_OFF + (size_t)gt * NE + e] = p;

        float pw = p;
        float myw = 0.f; int myi = 0;
        float wsum = 0.f;
#pragma unroll
        for (int r = 0; r < TOPK; ++r) {
            float bv = pw; int bi = e;
#pragma unroll
            for (int s = 1; s < 64; s <<= 1) {
                float ov = __shfl_xor(bv, s, 64);
                int   oi = __shfl_xor(bi, s, 64);
                if (ov > bv || (ov == bv && oi < bi)) { bv = ov; bi = oi; }
            }
            wsum += bv;
            if (lane == r) { myw = bv; myi = bi; }
            if (e == bi) { pw = -1.f; cnt++; }
        }
        if (lane < TOPK) {
            const float winv = 1.f / wsum;
            out[W_OFF + (size_t)gt * TOPK + lane] = myw * winv;
            out[I_OFF + (size_t)gt * TOPK + lane] = (float)myi;
        }
    }
    if (cnt) atomicAdd(&lc[e], cnt);
    __syncthreads();
    if (tid < NE) { int vv = lc[tid]; if (vv) atomicAdd(&counts[tid], vv); }
}

__global__ void zero_counts_k(int* c)
{
    if (threadIdx.x < NE) c[threadIdx.x] = 0;
}

// sign(load - 1/64) computed exactly: counts/2^18 is exact in fp32
__global__ void bias_k(const int* __restrict__ c, const float* __restrict__ eb,
                       float* __restrict__ out)
{
    int e = threadIdx.x;
    if (e < NE) {
        float load = (float)c[e] * (1.0f / 262144.0f);
        float err = load - 0.015625f;
        float sg = (err > 0.f) ? 1.f : ((err < 0.f) ? -1.f : 0.f);
        out[B_OFF + e] = eb[e] - 0.001f * sg;
    }
}

extern "C" void kernel_launch(void* const* d_in, const int* in_sizes, int n_in,
                              void* d_out, int out_size, void* d_ws, size_t ws_size,
                              hipStream_t stream)
{
    const float* x     = (const float*)d_in[0];
    const float* gw    = (const float*)d_in[1];
    const float* eb    = (const float*)d_in[2];
    const float* noise = (const float*)d_in[3];
    float* out = (float*)d_out;
    int* counts = (int*)d_ws;

    hipLaunchKernelGGL(zero_counts_k, dim3(1), dim3(64), 0, stream, counts);
    hipLaunchKernelGGL(router_fused, dim3(TT / 64), dim3(256), 0, stream,
                       x, gw, eb, noise, out, counts);
    hipLaunchKernelGGL(bias_k, dim3(1), dim3(64), 0, stream, counts, eb, out);
}